// Round 5
// baseline (887.213 us; speedup 1.0000x reference)
//
#include <hip/hip_runtime.h>
#include <cstdint>
#include <cstddef>

// Problem constants (from reference: B=4, C=64, H=288, W=432, TEM=6)
#define NB 4
#define NC 64
#define HH 288
#define WW 432
#define PW 72                      // W / TEM
#define NV (HH*WW)                 // 124416 vertices
#define R_PER ((HH-1)*PW)          // 20664 row (vertical) edges per phase
#define C_PER (HH*(PW-1))          // 20448 col (horizontal) edges per phase
#define X_PER (HH*PW)              // 20736 cross edges per phase pair
#define PAIRW (R_PER + C_PER)      // 41112 weight-layout per-phase block
#define ROWS_TOT (6*R_PER)         // 123984
#define ROWCOL (6*PAIRW)           // 246672
#define NE (ROWCOL + 5*X_PER)      // 350352 edges
#define NEB ((NE + 255)/256)       // 1369 blocks per batch (init grid)
#define EPT 4                      // edges per thread (ILP: 4 indep chains)
#define NEB4 ((NE + 1023)/1024)    // 343 blocks per batch (scan_full)
#define NTREE (NV-1)               // 124415
#define NROUNDS 18                 // round 0 fused in key0 + rounds 1..17
#define TAIL_START 6               // rounds 6..17 fused into tail_kernel
#define TBLK 512                   // tail block size
#define RB_CAP 4096                // root list cap (live comps @ r6 <= NV/64 = 1944)
#define CHUNK 4096
#define NCHUNK ((NE + CHUNK - 1)/CHUNK)   // 86
#define CSTR 32                    // per-batch counter stride (ints) = 128B pad
#define SLB 128                    // scan_list blocks per batch

typedef unsigned long long ull;

// ---- edge id -> endpoints, per the INDEX layout (rows ++ cols ++ cross) ----
__device__ __forceinline__ void index_uv(int e, int& u, int& v) {
    if (e < ROWS_TOT) {
        int t = e / R_PER, l = e - t * R_PER;
        int h = l / PW, x = l - h * PW;
        u = h * WW + t * PW + x; v = u + WW;
    } else if (e < ROWCOL) {
        int q = e - ROWS_TOT;
        int t = q / C_PER, l = q - t * C_PER;
        int h = l / (PW-1), x = l - h * (PW-1);
        u = h * WW + t * PW + x; v = u + 1;
    } else {
        int q = e - ROWCOL;
        int t = q / X_PER, l = q - t * X_PER;
        int h = l / PW, x = l - h * PW;
        u = h * WW + t * PW + x; v = u + PW;
    }
}

// root under parent forest; handles unbroken 2-cycles (mutual min edge) by
// rooting the smaller id — exactly the reference's (gp==idx)&(idx<parent) rule.
// rootOf2 takes the preloaded first hop p = par[c] so the common depth-1 case
// (p == c) completes with no additional dependent load.
__device__ __forceinline__ int rootOf2(const int* __restrict__ par, int c, int p) {
    while (true) {
        if (p == c) return c;
        int pp = par[p];
        if (pp == c) return c < p ? c : p;
        c = p; p = pp;
    }
}

__global__ __launch_bounds__(256) void init_kernel(int* comp, int* parent,
                                                   ull* minkey, unsigned char* mask,
                                                   int* cnt, int* found, int* done) {
    int i = blockIdx.x * 256 + threadIdx.x;
    int b = blockIdx.y;
    if (i < NV) {
        comp[(size_t)b*NV + i] = i;
        parent[(size_t)b*NV + i] = i;
        minkey[(size_t)b*NV + i] = ~0ULL;
    }
    if (i < NE) mask[(size_t)b*NE + i] = 0;
    if (b == 0 && i < 2*NB*CSTR) cnt[i] = 0;
    if (b == 0 && i < NB) { found[i] = 1; found[NB + i] = 0; done[i] = 0; }
}

// Stencil key kernel fused with Borůvka round 0 (~25 us, HBM-bound: 127 MB
// minimum input read — near roofline already).
__global__ __launch_bounds__(256) void key0_kernel(const float* __restrict__ fm,
                                                   ull* __restrict__ keys,
                                                   ull* __restrict__ minkey) {
    int i = blockIdx.x * 256 + threadIdx.x;
    int b = blockIdx.y;
    if (i >= NV) return;
    int h = i / WW, x = i - h * WW;
    int t = x / PW, xr = x - t * PW;
    bool hv = (h < HH-1);
    bool hh = (xr < PW-1);
    bool hx = (x < WW-PW);
    int ov = hv ? WW : 0;          // invalid -> reload self, diff = 0
    int oh = hh ? 1  : 0;
    int ox = hx ? PW : 0;
    const float* base = fm + (size_t)b * NC * NV + i;
    float sv = 0.f, sh_ = 0.f, sx = 0.f;
    #pragma unroll 8
    for (int ch = 0; ch < NC; ++ch) {
        const float* p = base + (size_t)ch * NV;
        float f0 = p[0];
        float dv = f0 - p[ov];
        float dh = f0 - p[oh];
        float dx = f0 - p[ox];
        sv += dv * dv; sh_ += dh * dh; sx += dx * dx;
    }
    ull* mk = minkey + (size_t)b * NV;
    ull* ky = keys + (size_t)b * NE;
    if (hv) {
        int e = t * PAIRW + h * PW + xr;
        ull k = ((ull)__float_as_uint(sv) << 32) | (unsigned int)e;
        ky[e] = k;
        int u, v; index_uv(e, u, v);
        atomicMin(&mk[u], k); atomicMin(&mk[v], k);
    }
    if (hh) {
        int e = t * PAIRW + R_PER + h * (PW-1) + xr;
        ull k = ((ull)__float_as_uint(sh_) << 32) | (unsigned int)e;
        ky[e] = k;
        int u, v; index_uv(e, u, v);
        atomicMin(&mk[u], k); atomicMin(&mk[v], k);
    }
    if (hx) {
        int e = ROWCOL + t * X_PER + h * PW + xr;
        ull k = ((ull)__float_as_uint(sx) << 32) | (unsigned int)e;
        ky[e] = k;
        int u, v; index_uv(e, u, v);
        atomicMin(&mk[u], k); atomicMin(&mk[v], k);
    }
}

// Round-1 scan: full sweep over all edges, 4 edges/thread software-pipelined
// (round-3 PMC: latency-bound single chains). Survivors compacted into
// list0/cnt[0] via per-wave ballot prefix + 1 global atomic per block.
__global__ __launch_bounds__(256) void scan_full_kernel(const ull* __restrict__ keys,
                                                        int* __restrict__ comp,
                                                        const int* __restrict__ parent,
                                                        ull* __restrict__ minkey,
                                                        int* __restrict__ list0,
                                                        int* __restrict__ cnt,
                                                        int* __restrict__ fCur) {
    const int tid = threadIdx.x;
    const int b = blockIdx.y;
    const int ebase = blockIdx.x * (256 * EPT) + tid;
    const size_t offV = (size_t)b * NV;
    const int* par = parent + offV;
    int* cmp = comp + offV;
    ull* mk = minkey + offV;
    const ull* ky = keys + (size_t)b * NE;

    int e[EPT], uu[EPT], vv[EPT], cu0[EPT], cv0[EPT], pu0[EPT], pv0[EPT];
    ull k[EPT];
    bool valid[EPT], live[EPT];
    #pragma unroll
    for (int j = 0; j < EPT; ++j) {
        e[j] = ebase + j * 256;
        valid[j] = e[j] < NE;
        int u = 0, v = 0;
        if (valid[j]) index_uv(e[j], u, v);
        uu[j] = u; vv[j] = v;
    }
    #pragma unroll
    for (int j = 0; j < EPT; ++j) {       // independent loads: comp + key
        cu0[j] = valid[j] ? cmp[uu[j]] : 0;
        cv0[j] = valid[j] ? cmp[vv[j]] : 0;
        k[j]   = valid[j] ? ky[e[j]] : 0;
    }
    #pragma unroll
    for (int j = 0; j < EPT; ++j) {       // independent loads: first par hop
        pu0[j] = valid[j] ? par[cu0[j]] : 0;
        pv0[j] = valid[j] ? par[cv0[j]] : 0;
    }
    #pragma unroll
    for (int j = 0; j < EPT; ++j) {
        live[j] = false;
        if (valid[j]) {
            int cu = rootOf2(par, cu0[j], pu0[j]);
            int cv = rootOf2(par, cv0[j], pv0[j]);
            if (cu0[j] != cu) cmp[uu[j]] = cu;   // benign race (fresh-root cache)
            if (cv0[j] != cv) cmp[vv[j]] = cv;
            live[j] = (cu != cv);
            if (live[j]) {
                if (k[j] < mk[cu]) atomicMin(&mk[cu], k[j]);  // pre-check filter
                if (k[j] < mk[cv]) atomicMin(&mk[cv], k[j]);
            }
        }
    }
    // block-aggregated emission (4 ballots, uniform control flow)
    __shared__ int s_w[4];
    __shared__ int s_bcnt;
    __shared__ int s_gb;
    const int lane = tid & 63;
    const int wid = tid >> 6;
    ull wl[EPT]; int wcnt = 0;
    #pragma unroll
    for (int j = 0; j < EPT; ++j) { wl[j] = __ballot(live[j] ? 1 : 0); wcnt += __popcll(wl[j]); }
    if (tid == 0) s_bcnt = 0;
    __syncthreads();
    if (lane == 0) s_w[wid] = wcnt ? atomicAdd(&s_bcnt, wcnt) : 0;
    __syncthreads();
    if (tid == 0 && s_bcnt) {
        s_gb = atomicAdd(&cnt[b * CSTR], s_bcnt);
        fCur[b] = 1;
    }
    __syncthreads();
    int pre = 0;
    #pragma unroll
    for (int j = 0; j < EPT; ++j) {
        if (live[j]) {
            int pos = s_gb + s_w[wid] + pre + __popcll(wl[j] & ((1ull << lane) - 1));
            list0[(size_t)b * NE + pos] = e[j];
        }
        pre += __popcll(wl[j]);
    }
}

// Rounds 2..5: scan over the compacted live-edge list (double-buffered),
// same 4-edges/thread pipelined structure. Reads list[rpar]/cnt[rpar], emits
// survivors into list[rpar^1]/cnt[rpar^1] (zeroed by the previous select).
__global__ __launch_bounds__(256) void scan_list_kernel(const ull* __restrict__ keys,
                                                        int* __restrict__ comp,
                                                        const int* __restrict__ parent,
                                                        ull* __restrict__ minkey,
                                                        int* __restrict__ list0,
                                                        int* __restrict__ list1,
                                                        int* __restrict__ cnt,
                                                        int rpar,
                                                        int* __restrict__ fCur,
                                                        const int* __restrict__ done) {
    const int b = blockIdx.y;
    if (done[b]) return;                      // block-uniform: safe pre-sync exit
    const int tid = threadIdx.x;
    const int n = cnt[rpar * NB * CSTR + b * CSTR];
    int* cw = &cnt[(rpar ^ 1) * NB * CSTR + b * CSTR];
    const int* lr = (rpar ? list1 : list0) + (size_t)b * NE;
    int* lw = (rpar ? list0 : list1) + (size_t)b * NE;
    const size_t offV = (size_t)b * NV;
    const int* par = parent + offV;
    int* cmp = comp + offV;
    ull* mk = minkey + offV;
    const ull* ky = keys + (size_t)b * NE;

    const int stride = SLB * 256 * EPT;
    const int nIter = (n + stride - 1) / stride;   // uniform across block
    const int lane = tid & 63;
    const int wid = tid >> 6;
    __shared__ int s_w[4];
    __shared__ int s_bcnt;
    __shared__ int s_gb;

    for (int it = 0; it < nIter; ++it) {
        const int ibase = it * stride + blockIdx.x * (256 * EPT) + tid;
        int e[EPT], uu[EPT], vv[EPT], cu0[EPT], cv0[EPT], pu0[EPT], pv0[EPT];
        ull k[EPT];
        bool valid[EPT], live[EPT];
        #pragma unroll
        for (int j = 0; j < EPT; ++j) {
            int i = ibase + j * 256;
            valid[j] = i < n;
            e[j] = valid[j] ? lr[i] : 0;
        }
        #pragma unroll
        for (int j = 0; j < EPT; ++j) {
            int u = 0, v = 0;
            if (valid[j]) index_uv(e[j], u, v);
            uu[j] = u; vv[j] = v;
        }
        #pragma unroll
        for (int j = 0; j < EPT; ++j) {
            cu0[j] = valid[j] ? cmp[uu[j]] : 0;
            cv0[j] = valid[j] ? cmp[vv[j]] : 0;
            k[j]   = valid[j] ? ky[e[j]] : 0;
        }
        #pragma unroll
        for (int j = 0; j < EPT; ++j) {
            pu0[j] = valid[j] ? par[cu0[j]] : 0;
            pv0[j] = valid[j] ? par[cv0[j]] : 0;
        }
        #pragma unroll
        for (int j = 0; j < EPT; ++j) {
            live[j] = false;
            if (valid[j]) {
                int cu = rootOf2(par, cu0[j], pu0[j]);
                int cv = rootOf2(par, cv0[j], pv0[j]);
                if (cu0[j] != cu) cmp[uu[j]] = cu;   // benign race
                if (cv0[j] != cv) cmp[vv[j]] = cv;
                live[j] = (cu != cv);
                if (live[j]) {
                    if (k[j] < mk[cu]) atomicMin(&mk[cu], k[j]);
                    if (k[j] < mk[cv]) atomicMin(&mk[cv], k[j]);
                }
            }
        }
        ull wl[EPT]; int wcnt = 0;
        #pragma unroll
        for (int j = 0; j < EPT; ++j) { wl[j] = __ballot(live[j] ? 1 : 0); wcnt += __popcll(wl[j]); }
        if (tid == 0) s_bcnt = 0;
        __syncthreads();
        if (lane == 0) s_w[wid] = wcnt ? atomicAdd(&s_bcnt, wcnt) : 0;
        __syncthreads();
        if (tid == 0 && s_bcnt) {
            s_gb = atomicAdd(cw, s_bcnt);
            fCur[b] = 1;
        }
        __syncthreads();
        int pre = 0;
        #pragma unroll
        for (int j = 0; j < EPT; ++j) {
            if (live[j]) {
                int pos = s_gb + s_w[wid] + pre + __popcll(wl[j] & ((1ull << lane) - 1));
                lw[pos] = e[j];
            }
            pre += __popcll(wl[j]);
        }
    }
}

// Per component: read winning edge, mark mask, hook parent, reset minkey.
// 4 consecutive vertices/thread with ulonglong4/int4 streaming loads. The
// full-NV sweep defines parent for ALL vertices — required for rounds 0..5
// where comp staleness is bootstrapped; rounds >= 6 use the sparse tail.
__global__ __launch_bounds__(256) void select_kernel(const int* __restrict__ comp,
                                                     int* __restrict__ parent,
                                                     ull* __restrict__ minkey,
                                                     unsigned char* __restrict__ mask,
                                                     const int* __restrict__ foundCur,
                                                     int* __restrict__ foundNext,
                                                     int* __restrict__ done,
                                                     int* __restrict__ cnt,
                                                     int zpar) {
    int gid = blockIdx.x * 256 + threadIdx.x;
    int b = blockIdx.y;
    int fc = foundCur[b];
    if (gid == 0) {
        foundNext[b] = 0;
        cnt[zpar * NB * CSTR + b * CSTR] = 0;
        if (fc == 0) done[b] = 1;                // monotone; visible to later scans
    }
    if (fc == 0) return;
    int c0 = gid * 4;
    if (c0 >= NV) return;
    size_t off = (size_t)b * NV;
    ulonglong4 kv = *reinterpret_cast<const ulonglong4*>(minkey + off + c0);
    int4 pv = *reinterpret_cast<const int4*>(parent + off + c0);
    ull kk[4] = {kv.x, kv.y, kv.z, kv.w};
    int pold[4] = {pv.x, pv.y, pv.z, pv.w};
    #pragma unroll
    for (int j = 0; j < 4; ++j) {
        int c = c0 + j;
        int pr = c;
        if (kk[j] != ~0ULL) {
            minkey[off + c] = ~0ULL;             // reset only touched slots
            int e = (int)(kk[j] & 0xffffffffu);
            mask[(size_t)b * NE + e] = 1;        // idempotent
            int u, v; index_uv(e, u, v);
            int cu = comp[off + u], cv = comp[off + v];
            pr = (cu == c) ? cv : cu;            // "other" component
        }
        if (pold[j] != pr) parent[off + c] = pr;
    }
}

// Rounds 6..17 fused: one block per batch (block-scope ordering via
// __syncthreads — grid syncs cost >=65 us on this part, rounds 1/2 evidence).
// Live components at round r <= NV/2^r (every live component merges), so at
// round 6: <=1944 comps, ~<=15k live edges — one 512-thread block suffices.
// Sparse select: scan emits each touched root exactly once via the atomicMin
// first-setter (old == ~0), select processes only that root list. Safe
// because comp values feeding round r are always refreshed to round-(r-1)
// roots by round r-1's scan (staleness depth exactly 1), so only current
// roots' parent entries are ever chased — the full-sweep reset was dead work.
// Entry: scan(5) emitted into cnt[parity 0]/list0; a pre-converged batch sees
// cnt[0] == 0 (zeroed by select(4)) and exits immediately.
__global__ __launch_bounds__(TBLK) void tail_kernel(const ull* __restrict__ keys,
                                                    int* __restrict__ comp,
                                                    int* __restrict__ parent,
                                                    ull* __restrict__ minkey,
                                                    unsigned char* __restrict__ mask,
                                                    int* __restrict__ list0,
                                                    int* __restrict__ list1,
                                                    const int* __restrict__ cnt,
                                                    int* __restrict__ rootbuf) {
    const int b = blockIdx.x;
    const int tid = threadIdx.x;
    const int lane = tid & 63;
    const int wid = tid >> 6;
    const size_t offV = (size_t)b * NV;
    int* cmp = comp + offV;
    int* par = parent + offV;
    ull* mk = minkey + offV;
    const ull* ky = keys + (size_t)b * NE;
    unsigned char* msk = mask + (size_t)b * NE;
    int* la = list0 + (size_t)b * NE;
    int* lb = list1 + (size_t)b * NE;
    int* rb = rootbuf + (size_t)b * RB_CAP;

    __shared__ int s_out;             // survivors emitted this round
    __shared__ int s_nr;              // roots emitted this round
    __shared__ int s_wb[TBLK/64];     // per-wave emission bases

    int rpar = TAIL_START & 1;        // = 0: scan(5) emitted into list0/cnt[0]
    int n = cnt[rpar * NB * CSTR + b * CSTR];

    for (int r = TAIL_START; r < NROUNDS && n > 0; ++r) {
        const int* lr = rpar ? lb : la;
        int* lw = rpar ? la : lb;
        if (tid == 0) { s_out = 0; s_nr = 0; }
        __syncthreads();
        // ---- scan phase (uniform trip count; only wave-local LDS inside) ----
        for (int base = 0; base < n; base += TBLK * EPT) {
            int e[EPT], uu[EPT], vv[EPT], cu0[EPT], cv0[EPT], pu0[EPT], pv0[EPT];
            ull k[EPT];
            bool valid[EPT], live[EPT];
            #pragma unroll
            for (int j = 0; j < EPT; ++j) {
                int i = base + tid + j * TBLK;
                valid[j] = i < n;
                e[j] = valid[j] ? lr[i] : 0;
            }
            #pragma unroll
            for (int j = 0; j < EPT; ++j) {
                int u = 0, v = 0;
                if (valid[j]) index_uv(e[j], u, v);
                uu[j] = u; vv[j] = v;
            }
            #pragma unroll
            for (int j = 0; j < EPT; ++j) {
                cu0[j] = valid[j] ? cmp[uu[j]] : 0;
                cv0[j] = valid[j] ? cmp[vv[j]] : 0;
                k[j]   = valid[j] ? ky[e[j]] : 0;
            }
            #pragma unroll
            for (int j = 0; j < EPT; ++j) {
                pu0[j] = valid[j] ? par[cu0[j]] : 0;
                pv0[j] = valid[j] ? par[cv0[j]] : 0;
            }
            #pragma unroll
            for (int j = 0; j < EPT; ++j) {
                live[j] = false;
                if (valid[j]) {
                    int cu = rootOf2(par, cu0[j], pu0[j]);
                    int cv = rootOf2(par, cv0[j], pv0[j]);
                    if (cu0[j] != cu) cmp[uu[j]] = cu;   // benign race
                    if (cv0[j] != cv) cmp[vv[j]] = cv;
                    live[j] = (cu != cv);
                    if (live[j]) {
                        if (k[j] < mk[cu]) {
                            ull old = atomicMin(&mk[cu], k[j]);
                            if (old == ~0ULL) rb[atomicAdd(&s_nr, 1)] = cu;  // first touch
                        }
                        if (k[j] < mk[cv]) {
                            ull old = atomicMin(&mk[cv], k[j]);
                            if (old == ~0ULL) rb[atomicAdd(&s_nr, 1)] = cv;
                        }
                    }
                }
            }
            ull wl[EPT]; int wcnt = 0;
            #pragma unroll
            for (int j = 0; j < EPT; ++j) { wl[j] = __ballot(live[j] ? 1 : 0); wcnt += __popcll(wl[j]); }
            if (lane == 0) s_wb[wid] = wcnt ? atomicAdd(&s_out, wcnt) : 0;
            int pre = 0;
            #pragma unroll
            for (int j = 0; j < EPT; ++j) {      // s_wb[wid]: same-wave write->read, in-order LDS
                if (live[j]) {
                    int pos = s_wb[wid] + pre + __popcll(wl[j] & ((1ull << lane) - 1));
                    lw[pos] = e[j];
                }
                pre += __popcll(wl[j]);
            }
        }
        __syncthreads();                         // all atomicMins + emissions visible
        int nout = s_out;
        int nr = s_nr;
        // ---- sparse select over this round's roots ----
        for (int i = tid; i < nr; i += TBLK) {
            int c = rb[i];
            ull k = mk[c];                       // final: no concurrent atomics now
            mk[c] = ~0ULL;                       // reset touched slot
            int e = (int)(k & 0xffffffffu);
            msk[e] = 1;
            int u, v; index_uv(e, u, v);
            int cu = cmp[u], cv = cmp[v];
            par[c] = (cu == c) ? cv : cu;        // hook to "other" component
        }
        __syncthreads();                         // hooks visible before next scan
        n = nout;
        rpar ^= 1;
    }
}

__global__ __launch_bounds__(256) void count_kernel(const unsigned char* __restrict__ mask,
                                                    int* __restrict__ counts) {
    int b = blockIdx.y, ck = blockIdx.x, t = threadIdx.x;
    const unsigned char* m = mask + (size_t)b * NE;
    int base_e = ck * CHUNK + t * 16;
    int cnt = 0;
    #pragma unroll
    for (int i = 0; i < 16; ++i) {
        int e = base_e + i;
        if (e < NE && m[e]) cnt++;
    }
    __shared__ int sh[256];
    sh[t] = cnt;
    __syncthreads();
    for (int o = 128; o > 0; o >>= 1) {
        if (t < o) sh[t] += sh[t + o];
        __syncthreads();
    }
    if (t == 0) counts[b * NCHUNK + ck] = sh[0];
}

// Write with inline offset computation (reduce over counts[0..ck-1]).
__global__ __launch_bounds__(256) void write_kernel(const unsigned char* __restrict__ mask,
                                                    const int* __restrict__ counts,
                                                    int* __restrict__ out) {
    int b = blockIdx.y, ck = blockIdx.x, t = threadIdx.x;
    __shared__ int sh[256];
    __shared__ int shOff[128];
    shOff[t & 127] = 0;
    __syncthreads();
    if (t < NCHUNK && t < ck) shOff[t] = counts[b * NCHUNK + t];
    __syncthreads();
    for (int o = 64; o > 0; o >>= 1) {
        if (t < o) shOff[t] += shOff[t + o];
        __syncthreads();
    }
    int blockOff = shOff[0];

    const unsigned char* m = mask + (size_t)b * NE;
    int base_e = ck * CHUNK + t * 16;
    int cnt = 0;
    #pragma unroll
    for (int i = 0; i < 16; ++i) {
        int e = base_e + i;
        if (e < NE && m[e]) cnt++;
    }
    sh[t] = cnt;
    __syncthreads();
    for (int o = 1; o < 256; o <<= 1) {          // Hillis-Steele inclusive scan
        int v = 0;
        if (t >= o) v = sh[t - o];
        __syncthreads();
        sh[t] += v;
        __syncthreads();
    }
    int pos = blockOff + (sh[t] - cnt);
    for (int i = 0; i < 16; ++i) {
        int e = base_e + i;
        if (e < NE && m[e]) {
            if (pos < NTREE) out[(size_t)b * NTREE + pos] = e;
            pos++;
        }
    }
}

extern "C" void kernel_launch(void* const* d_in, const int* in_sizes, int n_in,
                              void* d_out, int out_size, void* d_ws, size_t ws_size,
                              hipStream_t stream) {
    const float* fm = (const float*)d_in[0];
    int* out = (int*)d_out;   // reference output dtype is int32

    char* ws = (char*)d_ws;
    size_t off = 0;
    auto alloc = [&](size_t bytes) -> void* {
        void* p = ws + off;
        off += (bytes + 255) & ~(size_t)255;
        return p;
    };
    ull* keys    = (ull*)alloc((size_t)NB * NE * 8);
    ull* minkey  = (ull*)alloc((size_t)NB * NV * 8);
    int* comp    = (int*)alloc((size_t)NB * NV * 4);
    int* parent  = (int*)alloc((size_t)NB * NV * 4);
    unsigned char* mask = (unsigned char*)alloc((size_t)NB * NE);
    int* list0   = (int*)alloc((size_t)NB * NE * 4);
    int* list1   = (int*)alloc((size_t)NB * NE * 4);
    int* cnt     = (int*)alloc(2 * NB * CSTR * 4);
    int* rootbuf = (int*)alloc((size_t)NB * RB_CAP * 4);
    int* counts  = (int*)alloc((size_t)NB * NCHUNK * 4);
    int* found   = (int*)alloc(2 * NB * 4);
    int* done    = (int*)alloc(NB * 4);

    dim3 blk(256);
    dim3 gE(NEB, NB);
    dim3 gE4(NEB4, NB);
    dim3 gV((NV + 255) / 256, NB);
    dim3 gVS((NV/4 + 255) / 256, NB);     // select: 4 vertices/thread
    dim3 gL(SLB, NB);

    init_kernel<<<gE, blk, 0, stream>>>(comp, parent, minkey, mask, cnt, found, done);
    key0_kernel<<<gV, blk, 0, stream>>>(fm, keys, minkey);

    // Round 0 select (found[0..NB) preset to 1 by init; comp = identity).
    select_kernel<<<gVS, blk, 0, stream>>>(comp, parent, minkey, mask,
                                           found, found + NB, done, cnt, 0);
    // Round 1: full edge sweep + live-edge compaction into list0/cnt[0].
    scan_full_kernel<<<gE4, blk, 0, stream>>>(keys, comp, parent, minkey,
                                              list0, cnt, found + NB);
    select_kernel<<<gVS, blk, 0, stream>>>(comp, parent, minkey, mask,
                                           found + NB, found, done, cnt, 1);
    // Rounds 2..5: list-based scans. scan(r) reads list[r&1], emits
    // list[(r+1)&1]; select(r) zeroes cnt[r&1] for scan(r+1)'s emission.
    for (int r = 2; r < TAIL_START; ++r) {
        int* fCur  = found + (r & 1) * NB;
        int* fNext = found + ((r + 1) & 1) * NB;
        scan_list_kernel<<<gL, blk, 0, stream>>>(keys, comp, parent, minkey,
                                                 list0, list1, cnt, r & 1,
                                                 fCur, done);
        select_kernel<<<gVS, blk, 0, stream>>>(comp, parent, minkey, mask,
                                               fCur, fNext, done, cnt, r & 1);
    }
    // Rounds 6..17: one block per batch, __syncthreads-ordered scan+select.
    tail_kernel<<<dim3(NB), dim3(TBLK), 0, stream>>>(keys, comp, parent, minkey,
                                                     mask, list0, list1, cnt,
                                                     rootbuf);

    count_kernel<<<dim3(NCHUNK, NB), blk, 0, stream>>>(mask, counts);
    write_kernel<<<dim3(NCHUNK, NB), blk, 0, stream>>>(mask, counts, out);
}

// Round 8
// 571.220 us; speedup vs baseline: 1.5532x; 1.5532x over previous
//
#include <hip/hip_runtime.h>
#include <cstdint>
#include <cstddef>

// Problem constants (from reference: B=4, C=64, H=288, W=432, TEM=6)
#define NB 4
#define NC 64
#define HH 288
#define WW 432
#define PW 72                      // W / TEM
#define NV (HH*WW)                 // 124416 vertices
#define R_PER ((HH-1)*PW)          // 20664 row (vertical) edges per phase
#define C_PER (HH*(PW-1))          // 20448 col (horizontal) edges per phase
#define X_PER (HH*PW)              // 20736 cross edges per phase pair
#define PAIRW (R_PER + C_PER)      // 41112 weight-layout per-phase block
#define ROWS_TOT (6*R_PER)         // 123984
#define ROWCOL (6*PAIRW)           // 246672
#define NE (ROWCOL + 5*X_PER)      // 350352 edges
#define NEB ((NE + 255)/256)       // 1369 blocks per batch (init grid)
#define EPT 4                      // edges per thread (ILP: 4 indep chains)
#define NEB4 ((NE + 1023)/1024)    // 343 blocks per batch (scan_full)
#define NTREE (NV-1)               // 124415
#define NROUNDS 17                 // comps halve per round: <=1 after round 15; 16 = spare
#define CHUNK 4096
#define NCHUNK ((NE + CHUNK - 1)/CHUNK)   // 86
#define CSTR 32                    // per-batch counter stride (ints) = 128B pad
#define SLB 128                    // scan_list blocks per batch
#define SSB 64                     // select_sparse blocks per batch
#define RLCAP 65536                // root list capacity (round-1 roots <= 62208)

typedef unsigned long long ull;

// ---- edge id -> endpoints, per the INDEX layout (rows ++ cols ++ cross).
// NOTE: the reference's WEIGHT array is per-phase interleaved [r0,c0,...,x],
// while INDEX is [all rows ++ all cols ++ cross] — edge id e is a position in
// BOTH arrays, so its weight slot and its endpoints decode DIFFERENTLY. Any
// "vertex-local stencil endpoint" shortcut is wrong (round-7 failure).
__device__ __forceinline__ void index_uv(int e, int& u, int& v) {
    if (e < ROWS_TOT) {
        int t = e / R_PER, l = e - t * R_PER;
        int h = l / PW, x = l - h * PW;
        u = h * WW + t * PW + x; v = u + WW;
    } else if (e < ROWCOL) {
        int q = e - ROWS_TOT;
        int t = q / C_PER, l = q - t * C_PER;
        int h = l / (PW-1), x = l - h * (PW-1);
        u = h * WW + t * PW + x; v = u + 1;
    } else {
        int q = e - ROWCOL;
        int t = q / X_PER, l = q - t * X_PER;
        int h = l / PW, x = l - h * PW;
        u = h * WW + t * PW + x; v = u + PW;
    }
}

// root under parent forest; handles unbroken 2-cycles (mutual min edge) by
// rooting the smaller id — exactly the reference's (gp==idx)&(idx<parent) rule.
// rootOf2 takes the preloaded first hop p = par[c] so the common depth-1 case
// completes with no additional dependent load. Works with sparse select's
// stale chains: every chased entry was re-hooked in the round its owner was
// last live; cycles are always same-round 2-cycles (max-round argument).
__device__ __forceinline__ int rootOf2(const int* __restrict__ par, int c, int p) {
    while (true) {
        if (p == c) return c;
        int pp = par[p];
        if (pp == c) return c < p ? c : p;
        c = p; p = pp;
    }
}

__global__ __launch_bounds__(256) void init_kernel(int* comp, int* parent,
                                                   ull* minkey, unsigned char* mask,
                                                   int* cnt, int* rlc) {
    int i = blockIdx.x * 256 + threadIdx.x;
    int b = blockIdx.y;
    if (i < NV) {
        comp[(size_t)b*NV + i] = i;
        parent[(size_t)b*NV + i] = i;
        minkey[(size_t)b*NV + i] = ~0ULL;
    }
    if (i < NE) mask[(size_t)b*NE + i] = 0;
    if (b == 0 && i < 2*NB*CSTR) { cnt[i] = 0; rlc[i] = 0; }
}

// Stencil key kernel fused with Borůvka round 0 (~25 us, HBM-bound: 127 MB
// minimum input read). Weight-slot ids computed from the stencil; endpoints
// ALWAYS via index_uv (layout mismatch — see index_uv comment).
__global__ __launch_bounds__(256) void key0_kernel(const float* __restrict__ fm,
                                                   ull* __restrict__ keys,
                                                   ull* __restrict__ minkey) {
    int i = blockIdx.x * 256 + threadIdx.x;
    int b = blockIdx.y;
    if (i >= NV) return;
    int h = i / WW, x = i - h * WW;
    int t = x / PW, xr = x - t * PW;
    bool hv = (h < HH-1);
    bool hh = (xr < PW-1);
    bool hx = (x < WW-PW);
    int ov = hv ? WW : 0;          // invalid -> reload self, diff = 0
    int oh = hh ? 1  : 0;
    int ox = hx ? PW : 0;
    const float* base = fm + (size_t)b * NC * NV + i;
    float sv = 0.f, sh_ = 0.f, sx = 0.f;
    #pragma unroll 8
    for (int ch = 0; ch < NC; ++ch) {
        const float* p = base + (size_t)ch * NV;
        float f0 = p[0];
        float dv = f0 - p[ov];
        float dh = f0 - p[oh];
        float dx = f0 - p[ox];
        sv += dv * dv; sh_ += dh * dh; sx += dx * dx;
    }
    ull* mk = minkey + (size_t)b * NV;
    ull* ky = keys + (size_t)b * NE;
    if (hv) {
        int e = t * PAIRW + h * PW + xr;
        ull k = ((ull)__float_as_uint(sv) << 32) | (unsigned int)e;
        ky[e] = k;
        int u, v; index_uv(e, u, v);
        atomicMin(&mk[u], k); atomicMin(&mk[v], k);
    }
    if (hh) {
        int e = t * PAIRW + R_PER + h * (PW-1) + xr;
        ull k = ((ull)__float_as_uint(sh_) << 32) | (unsigned int)e;
        ky[e] = k;
        int u, v; index_uv(e, u, v);
        atomicMin(&mk[u], k); atomicMin(&mk[v], k);
    }
    if (hx) {
        int e = ROWCOL + t * X_PER + h * PW + xr;
        ull k = ((ull)__float_as_uint(sx) << 32) | (unsigned int)e;
        ky[e] = k;
        int u, v; index_uv(e, u, v);
        atomicMin(&mk[u], k); atomicMin(&mk[v], k);
    }
}

// Round-0 select: every vertex is a singleton winner — full-NV sweep,
// 4 vertices/thread vectorized. comp is identity here.
__global__ __launch_bounds__(256) void select0_kernel(const int* __restrict__ comp,
                                                      int* __restrict__ parent,
                                                      ull* __restrict__ minkey,
                                                      unsigned char* __restrict__ mask) {
    int gid = blockIdx.x * 256 + threadIdx.x;
    int b = blockIdx.y;
    int c0 = gid * 4;
    if (c0 >= NV) return;
    size_t off = (size_t)b * NV;
    ulonglong4 kv = *reinterpret_cast<const ulonglong4*>(minkey + off + c0);
    ull kk[4] = {kv.x, kv.y, kv.z, kv.w};
    #pragma unroll
    for (int j = 0; j < 4; ++j) {
        int c = c0 + j;
        if (kk[j] != ~0ULL) {
            minkey[off + c] = ~0ULL;
            int e = (int)(kk[j] & 0xffffffffu);
            mask[(size_t)b * NE + e] = 1;
            int u, v; index_uv(e, u, v);
            int cu = comp[off + u], cv = comp[off + v];
            parent[off + c] = (cu == c) ? cv : cu;
        }
    }
}

// Wave-aggregated root emission: recompute ballots twice (pass 1 total ->
// one global atomicAdd per wave; pass 2 scatter). Roots = atomicMin
// first-setters (old==~0), unique per slot per round.
#define EMIT_ROOTS(fcu, fcv, cuA, cvA, rlW, rlcSlot)                          \
    {                                                                         \
        int tot = 0;                                                          \
        _Pragma("unroll")                                                     \
        for (int j = 0; j < EPT; ++j) {                                       \
            tot += __popcll(__ballot(fcu[j] ? 1 : 0));                        \
            tot += __popcll(__ballot(fcv[j] ? 1 : 0));                        \
        }                                                                     \
        int base_ = 0;                                                        \
        if (lane == 0 && tot) base_ = atomicAdd(rlcSlot, tot);                \
        base_ = __shfl(base_, 0);                                             \
        ull ltm = (1ull << lane) - 1;                                         \
        int pre_ = 0;                                                         \
        _Pragma("unroll")                                                     \
        for (int j = 0; j < EPT; ++j) {                                       \
            ull bu = __ballot(fcu[j] ? 1 : 0);                                \
            if (fcu[j]) rlW[base_ + pre_ + __popcll(bu & ltm)] = cuA[j];      \
            pre_ += __popcll(bu);                                             \
            ull bv = __ballot(fcv[j] ? 1 : 0);                                \
            if (fcv[j]) rlW[base_ + pre_ + __popcll(bv & ltm)] = cvA[j];      \
            pre_ += __popcll(bv);                                             \
        }                                                                     \
    }

// Round-1 scan: full sweep over all edges, 4 edges/thread software-pipelined
// (round-3 PMC: latency-bound single chains; EPT=4 took 81->~50us).
// Survivors -> list0/cnt[0]; first-touched roots -> rlW/rlcW (for sparse
// select). One global atomic per block (edges) + one per wave (roots).
__global__ __launch_bounds__(256) void scan_full_kernel(const ull* __restrict__ keys,
                                                        int* __restrict__ comp,
                                                        const int* __restrict__ parent,
                                                        ull* __restrict__ minkey,
                                                        int* __restrict__ list0,
                                                        int* __restrict__ cnt,
                                                        int* __restrict__ rlWb,
                                                        int* __restrict__ rlcW) {
    const int tid = threadIdx.x;
    const int b = blockIdx.y;
    const int ebase = blockIdx.x * (256 * EPT) + tid;
    const size_t offV = (size_t)b * NV;
    const int* par = parent + offV;
    int* cmp = comp + offV;
    ull* mk = minkey + offV;
    const ull* ky = keys + (size_t)b * NE;
    int* rlW = rlWb + (size_t)b * RLCAP;

    int e[EPT], uu[EPT], vv[EPT], cu0[EPT], cv0[EPT], pu0[EPT], pv0[EPT];
    int cuA[EPT], cvA[EPT];
    ull k[EPT];
    bool valid[EPT], live[EPT], fcu[EPT], fcv[EPT];
    #pragma unroll
    for (int j = 0; j < EPT; ++j) {
        e[j] = ebase + j * 256;
        valid[j] = e[j] < NE;
        int u = 0, v = 0;
        if (valid[j]) index_uv(e[j], u, v);
        uu[j] = u; vv[j] = v;
    }
    #pragma unroll
    for (int j = 0; j < EPT; ++j) {       // independent loads: comp + key
        cu0[j] = valid[j] ? cmp[uu[j]] : 0;
        cv0[j] = valid[j] ? cmp[vv[j]] : 0;
        k[j]   = valid[j] ? ky[e[j]] : 0;
    }
    #pragma unroll
    for (int j = 0; j < EPT; ++j) {       // independent loads: first par hop
        pu0[j] = valid[j] ? par[cu0[j]] : 0;
        pv0[j] = valid[j] ? par[cv0[j]] : 0;
    }
    #pragma unroll
    for (int j = 0; j < EPT; ++j) {
        live[j] = false; fcu[j] = false; fcv[j] = false; cuA[j] = 0; cvA[j] = 0;
        if (valid[j]) {
            int cu = rootOf2(par, cu0[j], pu0[j]);
            int cv = rootOf2(par, cv0[j], pv0[j]);
            if (cu0[j] != cu) cmp[uu[j]] = cu;   // benign race (fresh-root cache)
            if (cv0[j] != cv) cmp[vv[j]] = cv;
            cuA[j] = cu; cvA[j] = cv;
            live[j] = (cu != cv);
            if (live[j]) {
                if (k[j] < mk[cu]) fcu[j] = (atomicMin(&mk[cu], k[j]) == ~0ULL);
                if (k[j] < mk[cv]) fcv[j] = (atomicMin(&mk[cv], k[j]) == ~0ULL);
            }
        }
    }
    const int lane = tid & 63;
    const int wid = tid >> 6;
    EMIT_ROOTS(fcu, fcv, cuA, cvA, rlW, &rlcW[b * CSTR])
    // block-aggregated edge emission (4 ballots, uniform control flow)
    __shared__ int s_w[4];
    __shared__ int s_bcnt;
    __shared__ int s_gb;
    ull wl[EPT]; int wcnt = 0;
    #pragma unroll
    for (int j = 0; j < EPT; ++j) { wl[j] = __ballot(live[j] ? 1 : 0); wcnt += __popcll(wl[j]); }
    if (tid == 0) s_bcnt = 0;
    __syncthreads();
    if (lane == 0) s_w[wid] = wcnt ? atomicAdd(&s_bcnt, wcnt) : 0;
    __syncthreads();
    if (tid == 0 && s_bcnt) s_gb = atomicAdd(&cnt[b * CSTR], s_bcnt);
    __syncthreads();
    int pre = 0;
    #pragma unroll
    for (int j = 0; j < EPT; ++j) {
        if (live[j]) {
            int pos = s_gb + s_w[wid] + pre + __popcll(wl[j] & ((1ull << lane) - 1));
            list0[(size_t)b * NE + pos] = e[j];
        }
        pre += __popcll(wl[j]);
    }
}

// Rounds 2..16: scan over the compacted live-edge list (double-buffered).
// Reads list[rpar]/cnt[rpar], emits survivors into list[rpar^1]/cnt[rpar^1]
// (zeroed by the previous select) and first-touched roots into rlW/rlcW.
// n==0 (converged batch) -> nIter=0, natural no-op (no done flag needed).
__global__ __launch_bounds__(256) void scan_list_kernel(const ull* __restrict__ keys,
                                                        int* __restrict__ comp,
                                                        const int* __restrict__ parent,
                                                        ull* __restrict__ minkey,
                                                        int* __restrict__ list0,
                                                        int* __restrict__ list1,
                                                        int* __restrict__ cnt,
                                                        int rpar,
                                                        int* __restrict__ rlWb,
                                                        int* __restrict__ rlcW) {
    const int b = blockIdx.y;
    const int tid = threadIdx.x;
    const int n = cnt[rpar * NB * CSTR + b * CSTR];
    int* cw = &cnt[(rpar ^ 1) * NB * CSTR + b * CSTR];
    const int* lr = (rpar ? list1 : list0) + (size_t)b * NE;
    int* lw = (rpar ? list0 : list1) + (size_t)b * NE;
    const size_t offV = (size_t)b * NV;
    const int* par = parent + offV;
    int* cmp = comp + offV;
    ull* mk = minkey + offV;
    const ull* ky = keys + (size_t)b * NE;
    int* rlW = rlWb + (size_t)b * RLCAP;

    const int stride = SLB * 256 * EPT;
    const int nIter = (n + stride - 1) / stride;   // uniform across block
    const int lane = tid & 63;
    const int wid = tid >> 6;
    __shared__ int s_w[4];
    __shared__ int s_bcnt;
    __shared__ int s_gb;

    for (int it = 0; it < nIter; ++it) {
        const int ibase = it * stride + blockIdx.x * (256 * EPT) + tid;
        int e[EPT], uu[EPT], vv[EPT], cu0[EPT], cv0[EPT], pu0[EPT], pv0[EPT];
        int cuA[EPT], cvA[EPT];
        ull k[EPT];
        bool valid[EPT], live[EPT], fcu[EPT], fcv[EPT];
        #pragma unroll
        for (int j = 0; j < EPT; ++j) {
            int i = ibase + j * 256;
            valid[j] = i < n;
            e[j] = valid[j] ? lr[i] : 0;
        }
        #pragma unroll
        for (int j = 0; j < EPT; ++j) {
            int u = 0, v = 0;
            if (valid[j]) index_uv(e[j], u, v);
            uu[j] = u; vv[j] = v;
        }
        #pragma unroll
        for (int j = 0; j < EPT; ++j) {
            cu0[j] = valid[j] ? cmp[uu[j]] : 0;
            cv0[j] = valid[j] ? cmp[vv[j]] : 0;
            k[j]   = valid[j] ? ky[e[j]] : 0;
        }
        #pragma unroll
        for (int j = 0; j < EPT; ++j) {
            pu0[j] = valid[j] ? par[cu0[j]] : 0;
            pv0[j] = valid[j] ? par[cv0[j]] : 0;
        }
        #pragma unroll
        for (int j = 0; j < EPT; ++j) {
            live[j] = false; fcu[j] = false; fcv[j] = false; cuA[j] = 0; cvA[j] = 0;
            if (valid[j]) {
                int cu = rootOf2(par, cu0[j], pu0[j]);
                int cv = rootOf2(par, cv0[j], pv0[j]);
                if (cu0[j] != cu) cmp[uu[j]] = cu;   // benign race
                if (cv0[j] != cv) cmp[vv[j]] = cv;
                cuA[j] = cu; cvA[j] = cv;
                live[j] = (cu != cv);
                if (live[j]) {
                    if (k[j] < mk[cu]) fcu[j] = (atomicMin(&mk[cu], k[j]) == ~0ULL);
                    if (k[j] < mk[cv]) fcv[j] = (atomicMin(&mk[cv], k[j]) == ~0ULL);
                }
            }
        }
        EMIT_ROOTS(fcu, fcv, cuA, cvA, rlW, &rlcW[b * CSTR])
        ull wl[EPT]; int wcnt = 0;
        #pragma unroll
        for (int j = 0; j < EPT; ++j) { wl[j] = __ballot(live[j] ? 1 : 0); wcnt += __popcll(wl[j]); }
        if (tid == 0) s_bcnt = 0;
        __syncthreads();
        if (lane == 0) s_w[wid] = wcnt ? atomicAdd(&s_bcnt, wcnt) : 0;
        __syncthreads();
        if (tid == 0 && s_bcnt) s_gb = atomicAdd(cw, s_bcnt);
        __syncthreads();
        int pre = 0;
        #pragma unroll
        for (int j = 0; j < EPT; ++j) {
            if (live[j]) {
                int pos = s_gb + s_w[wid] + pre + __popcll(wl[j] & ((1ull << lane) - 1));
                lw[pos] = e[j];
            }
            pre += __popcll(wl[j]);
        }
    }
}

// Sparse select (rounds >= 1): process only this round's touched roots (from
// the scan's first-setter list). For each root: read winning edge, mark mask,
// hook parent, reset minkey. comp[u]/comp[v] are current-round roots (scan
// writeback). Also zeroes the cnt/rlc slots the NEXT scan emits into.
__global__ __launch_bounds__(256) void select_sparse_kernel(const int* __restrict__ comp,
                                                            int* __restrict__ parent,
                                                            ull* __restrict__ minkey,
                                                            unsigned char* __restrict__ mask,
                                                            const int* __restrict__ rlRb,
                                                            const int* __restrict__ rlcCur,
                                                            int* __restrict__ cntZ,
                                                            int* __restrict__ rlcZ) {
    const int b = blockIdx.y;
    if (blockIdx.x == 0 && threadIdx.x == 0) {
        cntZ[b * CSTR] = 0;              // edge buffer next scan emits into
        rlcZ[b * CSTR] = 0;              // root counter next scan emits into
    }
    const int nr = rlcCur[b * CSTR];
    const int* rlR = rlRb + (size_t)b * RLCAP;
    const size_t off = (size_t)b * NV;
    for (int i = blockIdx.x * 256 + threadIdx.x; i < nr; i += SSB * 256) {
        int c = rlR[i];
        ull k = minkey[off + c];         // final: scan is complete
        minkey[off + c] = ~0ULL;
        int e = (int)(k & 0xffffffffu);
        mask[(size_t)b * NE + e] = 1;
        int u, v; index_uv(e, u, v);
        int cu = comp[off + u], cv = comp[off + v];
        parent[off + c] = (cu == c) ? cv : cu;
    }
}

__global__ __launch_bounds__(256) void count_kernel(const unsigned char* __restrict__ mask,
                                                    int* __restrict__ counts) {
    int b = blockIdx.y, ck = blockIdx.x, t = threadIdx.x;
    const unsigned char* m = mask + (size_t)b * NE;
    int base_e = ck * CHUNK + t * 16;
    int cnt = 0;
    #pragma unroll
    for (int i = 0; i < 16; ++i) {
        int e = base_e + i;
        if (e < NE && m[e]) cnt++;
    }
    __shared__ int sh[256];
    sh[t] = cnt;
    __syncthreads();
    for (int o = 128; o > 0; o >>= 1) {
        if (t < o) sh[t] += sh[t + o];
        __syncthreads();
    }
    if (t == 0) counts[b * NCHUNK + ck] = sh[0];
}

// Write with inline offset computation (reduce over counts[0..ck-1]).
__global__ __launch_bounds__(256) void write_kernel(const unsigned char* __restrict__ mask,
                                                    const int* __restrict__ counts,
                                                    int* __restrict__ out) {
    int b = blockIdx.y, ck = blockIdx.x, t = threadIdx.x;
    __shared__ int sh[256];
    __shared__ int shOff[128];
    shOff[t & 127] = 0;
    __syncthreads();
    if (t < NCHUNK && t < ck) shOff[t] = counts[b * NCHUNK + t];
    __syncthreads();
    for (int o = 64; o > 0; o >>= 1) {
        if (t < o) shOff[t] += shOff[t + o];
        __syncthreads();
    }
    int blockOff = shOff[0];

    const unsigned char* m = mask + (size_t)b * NE;
    int base_e = ck * CHUNK + t * 16;
    int cnt = 0;
    #pragma unroll
    for (int i = 0; i < 16; ++i) {
        int e = base_e + i;
        if (e < NE && m[e]) cnt++;
    }
    sh[t] = cnt;
    __syncthreads();
    for (int o = 1; o < 256; o <<= 1) {          // Hillis-Steele inclusive scan
        int v = 0;
        if (t >= o) v = sh[t - o];
        __syncthreads();
        sh[t] += v;
        __syncthreads();
    }
    int pos = blockOff + (sh[t] - cnt);
    for (int i = 0; i < 16; ++i) {
        int e = base_e + i;
        if (e < NE && m[e]) {
            if (pos < NTREE) out[(size_t)b * NTREE + pos] = e;
            pos++;
        }
    }
}

extern "C" void kernel_launch(void* const* d_in, const int* in_sizes, int n_in,
                              void* d_out, int out_size, void* d_ws, size_t ws_size,
                              hipStream_t stream) {
    const float* fm = (const float*)d_in[0];
    int* out = (int*)d_out;   // reference output dtype is int32

    char* ws = (char*)d_ws;
    size_t off = 0;
    auto alloc = [&](size_t bytes) -> void* {
        void* p = ws + off;
        off += (bytes + 255) & ~(size_t)255;
        return p;
    };
    ull* keys    = (ull*)alloc((size_t)NB * NE * 8);
    ull* minkey  = (ull*)alloc((size_t)NB * NV * 8);
    int* comp    = (int*)alloc((size_t)NB * NV * 4);
    int* parent  = (int*)alloc((size_t)NB * NV * 4);
    unsigned char* mask = (unsigned char*)alloc((size_t)NB * NE);
    int* list0   = (int*)alloc((size_t)NB * NE * 4);
    int* list1   = (int*)alloc((size_t)NB * NE * 4);
    int* cnt     = (int*)alloc(2 * NB * CSTR * 4);
    int* rl      = (int*)alloc(2 * (size_t)NB * RLCAP * 4);
    int* rlc     = (int*)alloc(2 * NB * CSTR * 4);
    int* counts  = (int*)alloc((size_t)NB * NCHUNK * 4);

    dim3 blk(256);
    dim3 gE(NEB, NB);
    dim3 gE4(NEB4, NB);
    dim3 gV((NV + 255) / 256, NB);
    dim3 gVS((NV/4 + 255) / 256, NB);     // select0: 4 vertices/thread
    dim3 gL(SLB, NB);
    dim3 gS(SSB, NB);

    init_kernel<<<gE, blk, 0, stream>>>(comp, parent, minkey, mask, cnt, rlc);
    key0_kernel<<<gV, blk, 0, stream>>>(fm, keys, minkey);
    // Round 0: full select (every vertex is a winner; comp = identity).
    select0_kernel<<<gVS, blk, 0, stream>>>(comp, parent, minkey, mask);
    // Round 1: full edge sweep -> list0/cnt[0] + roots -> rl[1]/rlc[1].
    scan_full_kernel<<<gE4, blk, 0, stream>>>(keys, comp, parent, minkey,
                                              list0, cnt,
                                              rl + (size_t)NB * RLCAP,
                                              rlc + NB * CSTR);
    select_sparse_kernel<<<gS, blk, 0, stream>>>(comp, parent, minkey, mask,
                                                 rl + (size_t)NB * RLCAP,
                                                 rlc + NB * CSTR,
                                                 cnt + NB * CSTR,   // zero cnt[1]
                                                 rlc);              // zero rlc[0]
    // Rounds 2..16: scan(r) reads cnt[r&1] edges, emits cnt[(r+1)&1] + roots
    // rlc[r&1]; select(r) consumes rlc[r&1], zeroes cnt[r&1] & rlc[(r+1)&1].
    for (int r = 2; r < NROUNDS; ++r) {
        int rp = r & 1, ro = (r + 1) & 1;
        scan_list_kernel<<<gL, blk, 0, stream>>>(keys, comp, parent, minkey,
                                                 list0, list1, cnt, rp,
                                                 rl + (size_t)rp * NB * RLCAP,
                                                 rlc + rp * NB * CSTR);
        select_sparse_kernel<<<gS, blk, 0, stream>>>(comp, parent, minkey, mask,
                                                     rl + (size_t)rp * NB * RLCAP,
                                                     rlc + rp * NB * CSTR,
                                                     cnt + rp * NB * CSTR,
                                                     rlc + ro * NB * CSTR);
    }

    count_kernel<<<dim3(NCHUNK, NB), blk, 0, stream>>>(mask, counts);
    write_kernel<<<dim3(NCHUNK, NB), blk, 0, stream>>>(mask, counts, out);
}

// Round 11
// 550.963 us; speedup vs baseline: 1.6103x; 1.0368x over previous
//
#include <hip/hip_runtime.h>
#include <cstdint>
#include <cstddef>

// Problem constants (from reference: B=4, C=64, H=288, W=432, TEM=6)
#define NB 4
#define NC 64
#define HH 288
#define WW 432
#define PW 72                      // W / TEM
#define NV (HH*WW)                 // 124416 vertices
#define R_PER ((HH-1)*PW)          // 20664 row (vertical) edges per phase
#define C_PER (HH*(PW-1))          // 20448 col (horizontal) edges per phase
#define X_PER (HH*PW)              // 20736 cross edges per phase pair
#define PAIRW (R_PER + C_PER)      // 41112 weight-layout per-phase block
#define ROWS_TOT (6*R_PER)         // 123984
#define ROWCOL (6*PAIRW)           // 246672
#define NE (ROWCOL + 5*X_PER)      // 350352 edges
#define NEB ((NE + 255)/256)       // 1369 blocks per batch (init grid)
#define EPT 4                      // edges per thread (ILP: 4 indep chains)
#define NEB4 ((NE + 1023)/1024)    // 343 blocks per batch (scan_full)
#define NTREE (NV-1)               // 124415
#define NROUNDS 17                 // comps halve per round: <=1 after round 15; 16 = spare
#define TAIL_START 10              // rounds 10..16 in one single-block-per-batch kernel
#define TBLK 512                   // tail block size (round-5-verified geometry)
#define RB_CAP 4096                // tail root list (comps@10 <= NV/2^10 = 121)
#define CHUNK 4096
#define NCHUNK ((NE + CHUNK - 1)/CHUNK)   // 86
#define CSTR 32                    // per-batch counter stride (ints) = 128B pad
#define SLB 128                    // scan_list blocks per batch
#define SSB 64                     // select_sparse blocks per batch
#define RLCAP 65536                // root list capacity (round-1 roots <= 62208)

typedef unsigned long long ull;

// ---- edge id -> endpoints, per the INDEX layout (rows ++ cols ++ cross).
// NOTE: the reference's WEIGHT array is per-phase interleaved [r0,c0,...,x],
// while INDEX is [all rows ++ all cols ++ cross] — edge id e is a position in
// BOTH arrays, so its weight slot and its endpoints decode DIFFERENTLY. Any
// "vertex-local stencil endpoint" shortcut is wrong (round-7 failure).
__device__ __forceinline__ void index_uv(int e, int& u, int& v) {
    if (e < ROWS_TOT) {
        int t = e / R_PER, l = e - t * R_PER;
        int h = l / PW, x = l - h * PW;
        u = h * WW + t * PW + x; v = u + WW;
    } else if (e < ROWCOL) {
        int q = e - ROWS_TOT;
        int t = q / C_PER, l = q - t * C_PER;
        int h = l / (PW-1), x = l - h * (PW-1);
        u = h * WW + t * PW + x; v = u + 1;
    } else {
        int q = e - ROWCOL;
        int t = q / X_PER, l = q - t * X_PER;
        int h = l / PW, x = l - h * PW;
        u = h * WW + t * PW + x; v = u + PW;
    }
}

// root under parent forest; handles unbroken 2-cycles (mutual min edge) by
// rooting the smaller id — exactly the reference's (gp==idx)&(idx<parent) rule.
// rootOf2 takes the preloaded first hop p = par[c] so the common depth-1 case
// completes with no additional dependent load.
__device__ __forceinline__ int rootOf2(const int* __restrict__ par, int c, int p) {
    while (true) {
        if (p == c) return c;
        int pp = par[p];
        if (pp == c) return c < p ? c : p;
        c = p; p = pp;
    }
}

__global__ __launch_bounds__(256) void init_kernel(int* comp, int* parent,
                                                   ull* minkey, unsigned char* mask,
                                                   int* cnt, int* rlc) {
    int i = blockIdx.x * 256 + threadIdx.x;
    int b = blockIdx.y;
    if (i < NV) {
        comp[(size_t)b*NV + i] = i;
        parent[(size_t)b*NV + i] = i;
        minkey[(size_t)b*NV + i] = ~0ULL;
    }
    if (i < NE) mask[(size_t)b*NE + i] = 0;
    if (b == 0 && i < 2*NB*CSTR) { cnt[i] = 0; rlc[i] = 0; }
}

// Stencil key kernel fused with Borůvka round 0 (~25 us, HBM-bound: 127 MB
// minimum input read). Weight-slot ids computed from the stencil; endpoints
// ALWAYS via index_uv (layout mismatch — see index_uv comment).
__global__ __launch_bounds__(256) void key0_kernel(const float* __restrict__ fm,
                                                   ull* __restrict__ keys,
                                                   ull* __restrict__ minkey) {
    int i = blockIdx.x * 256 + threadIdx.x;
    int b = blockIdx.y;
    if (i >= NV) return;
    int h = i / WW, x = i - h * WW;
    int t = x / PW, xr = x - t * PW;
    bool hv = (h < HH-1);
    bool hh = (xr < PW-1);
    bool hx = (x < WW-PW);
    int ov = hv ? WW : 0;          // invalid -> reload self, diff = 0
    int oh = hh ? 1  : 0;
    int ox = hx ? PW : 0;
    const float* base = fm + (size_t)b * NC * NV + i;
    float sv = 0.f, sh_ = 0.f, sx = 0.f;
    #pragma unroll 8
    for (int ch = 0; ch < NC; ++ch) {
        const float* p = base + (size_t)ch * NV;
        float f0 = p[0];
        float dv = f0 - p[ov];
        float dh = f0 - p[oh];
        float dx = f0 - p[ox];
        sv += dv * dv; sh_ += dh * dh; sx += dx * dx;
    }
    ull* mk = minkey + (size_t)b * NV;
    ull* ky = keys + (size_t)b * NE;
    if (hv) {
        int e = t * PAIRW + h * PW + xr;
        ull k = ((ull)__float_as_uint(sv) << 32) | (unsigned int)e;
        ky[e] = k;
        int u, v; index_uv(e, u, v);
        atomicMin(&mk[u], k); atomicMin(&mk[v], k);
    }
    if (hh) {
        int e = t * PAIRW + R_PER + h * (PW-1) + xr;
        ull k = ((ull)__float_as_uint(sh_) << 32) | (unsigned int)e;
        ky[e] = k;
        int u, v; index_uv(e, u, v);
        atomicMin(&mk[u], k); atomicMin(&mk[v], k);
    }
    if (hx) {
        int e = ROWCOL + t * X_PER + h * PW + xr;
        ull k = ((ull)__float_as_uint(sx) << 32) | (unsigned int)e;
        ky[e] = k;
        int u, v; index_uv(e, u, v);
        atomicMin(&mk[u], k); atomicMin(&mk[v], k);
    }
}

// Round-0 select: every vertex is a singleton winner — full-NV sweep,
// 4 vertices/thread vectorized. comp is identity here.
__global__ __launch_bounds__(256) void select0_kernel(const int* __restrict__ comp,
                                                      int* __restrict__ parent,
                                                      ull* __restrict__ minkey,
                                                      unsigned char* __restrict__ mask) {
    int gid = blockIdx.x * 256 + threadIdx.x;
    int b = blockIdx.y;
    int c0 = gid * 4;
    if (c0 >= NV) return;
    size_t off = (size_t)b * NV;
    ulonglong4 kv = *reinterpret_cast<const ulonglong4*>(minkey + off + c0);
    ull kk[4] = {kv.x, kv.y, kv.z, kv.w};
    #pragma unroll
    for (int j = 0; j < 4; ++j) {
        int c = c0 + j;
        if (kk[j] != ~0ULL) {
            minkey[off + c] = ~0ULL;
            int e = (int)(kk[j] & 0xffffffffu);
            mask[(size_t)b * NE + e] = 1;
            int u, v; index_uv(e, u, v);
            int cu = comp[off + u], cv = comp[off + v];
            parent[off + c] = (cu == c) ? cv : cu;
        }
    }
}

// Wave-aggregated root emission: recompute ballots twice (pass 1 total ->
// one global atomicAdd per wave; pass 2 scatter). Roots = atomicMin
// first-setters (old==~0), unique per slot per round.
#define EMIT_ROOTS(fcu, fcv, cuA, cvA, rlW, rlcSlot)                          \
    {                                                                         \
        int tot = 0;                                                          \
        _Pragma("unroll")                                                     \
        for (int j = 0; j < EPT; ++j) {                                       \
            tot += __popcll(__ballot(fcu[j] ? 1 : 0));                        \
            tot += __popcll(__ballot(fcv[j] ? 1 : 0));                        \
        }                                                                     \
        int base_ = 0;                                                        \
        if (lane == 0 && tot) base_ = atomicAdd(rlcSlot, tot);                \
        base_ = __shfl(base_, 0);                                             \
        ull ltm = (1ull << lane) - 1;                                         \
        int pre_ = 0;                                                         \
        _Pragma("unroll")                                                     \
        for (int j = 0; j < EPT; ++j) {                                       \
            ull bu = __ballot(fcu[j] ? 1 : 0);                                \
            if (fcu[j]) rlW[base_ + pre_ + __popcll(bu & ltm)] = cuA[j];      \
            pre_ += __popcll(bu);                                             \
            ull bv = __ballot(fcv[j] ? 1 : 0);                                \
            if (fcv[j]) rlW[base_ + pre_ + __popcll(bv & ltm)] = cvA[j];      \
            pre_ += __popcll(bv);                                             \
        }                                                                     \
    }

// Round-1 scan: full sweep over all edges, 4 edges/thread software-pipelined.
// Survivors -> list0/cnt[0]; first-touched roots -> rlW/rlcW (sparse select).
__global__ __launch_bounds__(256) void scan_full_kernel(const ull* __restrict__ keys,
                                                        int* __restrict__ comp,
                                                        const int* __restrict__ parent,
                                                        ull* __restrict__ minkey,
                                                        int* __restrict__ list0,
                                                        int* __restrict__ cnt,
                                                        int* __restrict__ rlWb,
                                                        int* __restrict__ rlcW) {
    const int tid = threadIdx.x;
    const int b = blockIdx.y;
    const int ebase = blockIdx.x * (256 * EPT) + tid;
    const size_t offV = (size_t)b * NV;
    const int* par = parent + offV;
    int* cmp = comp + offV;
    ull* mk = minkey + offV;
    const ull* ky = keys + (size_t)b * NE;
    int* rlW = rlWb + (size_t)b * RLCAP;

    int e[EPT], uu[EPT], vv[EPT], cu0[EPT], cv0[EPT], pu0[EPT], pv0[EPT];
    int cuA[EPT], cvA[EPT];
    ull k[EPT];
    bool valid[EPT], live[EPT], fcu[EPT], fcv[EPT];
    #pragma unroll
    for (int j = 0; j < EPT; ++j) {
        e[j] = ebase + j * 256;
        valid[j] = e[j] < NE;
        int u = 0, v = 0;
        if (valid[j]) index_uv(e[j], u, v);
        uu[j] = u; vv[j] = v;
    }
    #pragma unroll
    for (int j = 0; j < EPT; ++j) {       // independent loads: comp + key
        cu0[j] = valid[j] ? cmp[uu[j]] : 0;
        cv0[j] = valid[j] ? cmp[vv[j]] : 0;
        k[j]   = valid[j] ? ky[e[j]] : 0;
    }
    #pragma unroll
    for (int j = 0; j < EPT; ++j) {       // independent loads: first par hop
        pu0[j] = valid[j] ? par[cu0[j]] : 0;
        pv0[j] = valid[j] ? par[cv0[j]] : 0;
    }
    #pragma unroll
    for (int j = 0; j < EPT; ++j) {
        live[j] = false; fcu[j] = false; fcv[j] = false; cuA[j] = 0; cvA[j] = 0;
        if (valid[j]) {
            int cu = rootOf2(par, cu0[j], pu0[j]);
            int cv = rootOf2(par, cv0[j], pv0[j]);
            if (cu0[j] != cu) cmp[uu[j]] = cu;   // benign race (fresh-root cache)
            if (cv0[j] != cv) cmp[vv[j]] = cv;
            cuA[j] = cu; cvA[j] = cv;
            live[j] = (cu != cv);
            if (live[j]) {
                if (k[j] < mk[cu]) fcu[j] = (atomicMin(&mk[cu], k[j]) == ~0ULL);
                if (k[j] < mk[cv]) fcv[j] = (atomicMin(&mk[cv], k[j]) == ~0ULL);
            }
        }
    }
    const int lane = tid & 63;
    const int wid = tid >> 6;
    EMIT_ROOTS(fcu, fcv, cuA, cvA, rlW, &rlcW[b * CSTR])
    // block-aggregated edge emission (4 ballots, uniform control flow)
    __shared__ int s_w[4];
    __shared__ int s_bcnt;
    __shared__ int s_gb;
    ull wl[EPT]; int wcnt = 0;
    #pragma unroll
    for (int j = 0; j < EPT; ++j) { wl[j] = __ballot(live[j] ? 1 : 0); wcnt += __popcll(wl[j]); }
    if (tid == 0) s_bcnt = 0;
    __syncthreads();
    if (lane == 0) s_w[wid] = wcnt ? atomicAdd(&s_bcnt, wcnt) : 0;
    __syncthreads();
    if (tid == 0 && s_bcnt) s_gb = atomicAdd(&cnt[b * CSTR], s_bcnt);
    __syncthreads();
    int pre = 0;
    #pragma unroll
    for (int j = 0; j < EPT; ++j) {
        if (live[j]) {
            int pos = s_gb + s_w[wid] + pre + __popcll(wl[j] & ((1ull << lane) - 1));
            list0[(size_t)b * NE + pos] = e[j];
        }
        pre += __popcll(wl[j]);
    }
}

// Rounds 2..9: scan over the compacted live-edge list (double-buffered).
// n==0 (converged batch) -> nIter=0, natural no-op.
__global__ __launch_bounds__(256) void scan_list_kernel(const ull* __restrict__ keys,
                                                        int* __restrict__ comp,
                                                        const int* __restrict__ parent,
                                                        ull* __restrict__ minkey,
                                                        int* __restrict__ list0,
                                                        int* __restrict__ list1,
                                                        int* __restrict__ cnt,
                                                        int rpar,
                                                        int* __restrict__ rlWb,
                                                        int* __restrict__ rlcW) {
    const int b = blockIdx.y;
    const int tid = threadIdx.x;
    const int n = cnt[rpar * NB * CSTR + b * CSTR];
    int* cw = &cnt[(rpar ^ 1) * NB * CSTR + b * CSTR];
    const int* lr = (rpar ? list1 : list0) + (size_t)b * NE;
    int* lw = (rpar ? list0 : list1) + (size_t)b * NE;
    const size_t offV = (size_t)b * NV;
    const int* par = parent + offV;
    int* cmp = comp + offV;
    ull* mk = minkey + offV;
    const ull* ky = keys + (size_t)b * NE;
    int* rlW = rlWb + (size_t)b * RLCAP;

    const int stride = SLB * 256 * EPT;
    const int nIter = (n + stride - 1) / stride;   // uniform across block
    const int lane = tid & 63;
    const int wid = tid >> 6;
    __shared__ int s_w[4];
    __shared__ int s_bcnt;
    __shared__ int s_gb;

    for (int it = 0; it < nIter; ++it) {
        const int ibase = it * stride + blockIdx.x * (256 * EPT) + tid;
        int e[EPT], uu[EPT], vv[EPT], cu0[EPT], cv0[EPT], pu0[EPT], pv0[EPT];
        int cuA[EPT], cvA[EPT];
        ull k[EPT];
        bool valid[EPT], live[EPT], fcu[EPT], fcv[EPT];
        #pragma unroll
        for (int j = 0; j < EPT; ++j) {
            int i = ibase + j * 256;
            valid[j] = i < n;
            e[j] = valid[j] ? lr[i] : 0;
        }
        #pragma unroll
        for (int j = 0; j < EPT; ++j) {
            int u = 0, v = 0;
            if (valid[j]) index_uv(e[j], u, v);
            uu[j] = u; vv[j] = v;
        }
        #pragma unroll
        for (int j = 0; j < EPT; ++j) {
            cu0[j] = valid[j] ? cmp[uu[j]] : 0;
            cv0[j] = valid[j] ? cmp[vv[j]] : 0;
            k[j]   = valid[j] ? ky[e[j]] : 0;
        }
        #pragma unroll
        for (int j = 0; j < EPT; ++j) {
            pu0[j] = valid[j] ? par[cu0[j]] : 0;
            pv0[j] = valid[j] ? par[cv0[j]] : 0;
        }
        #pragma unroll
        for (int j = 0; j < EPT; ++j) {
            live[j] = false; fcu[j] = false; fcv[j] = false; cuA[j] = 0; cvA[j] = 0;
            if (valid[j]) {
                int cu = rootOf2(par, cu0[j], pu0[j]);
                int cv = rootOf2(par, cv0[j], pv0[j]);
                if (cu0[j] != cu) cmp[uu[j]] = cu;   // benign race
                if (cv0[j] != cv) cmp[vv[j]] = cv;
                cuA[j] = cu; cvA[j] = cv;
                live[j] = (cu != cv);
                if (live[j]) {
                    if (k[j] < mk[cu]) fcu[j] = (atomicMin(&mk[cu], k[j]) == ~0ULL);
                    if (k[j] < mk[cv]) fcv[j] = (atomicMin(&mk[cv], k[j]) == ~0ULL);
                }
            }
        }
        EMIT_ROOTS(fcu, fcv, cuA, cvA, rlW, &rlcW[b * CSTR])
        ull wl[EPT]; int wcnt = 0;
        #pragma unroll
        for (int j = 0; j < EPT; ++j) { wl[j] = __ballot(live[j] ? 1 : 0); wcnt += __popcll(wl[j]); }
        if (tid == 0) s_bcnt = 0;
        __syncthreads();
        if (lane == 0) s_w[wid] = wcnt ? atomicAdd(&s_bcnt, wcnt) : 0;
        __syncthreads();
        if (tid == 0 && s_bcnt) s_gb = atomicAdd(cw, s_bcnt);
        __syncthreads();
        int pre = 0;
        #pragma unroll
        for (int j = 0; j < EPT; ++j) {
            if (live[j]) {
                int pos = s_gb + s_w[wid] + pre + __popcll(wl[j] & ((1ull << lane) - 1));
                lw[pos] = e[j];
            }
            pre += __popcll(wl[j]);
        }
    }
}

// Sparse select (rounds 1..9): process only this round's touched roots.
// Also zeroes the cnt/rlc slots the NEXT scan emits into.
__global__ __launch_bounds__(256) void select_sparse_kernel(const int* __restrict__ comp,
                                                            int* __restrict__ parent,
                                                            ull* __restrict__ minkey,
                                                            unsigned char* __restrict__ mask,
                                                            const int* __restrict__ rlRb,
                                                            const int* __restrict__ rlcCur,
                                                            int* __restrict__ cntZ,
                                                            int* __restrict__ rlcZ) {
    const int b = blockIdx.y;
    if (blockIdx.x == 0 && threadIdx.x == 0) {
        cntZ[b * CSTR] = 0;              // edge buffer next scan emits into
        rlcZ[b * CSTR] = 0;              // root counter next scan emits into
    }
    const int nr = rlcCur[b * CSTR];
    const int* rlR = rlRb + (size_t)b * RLCAP;
    const size_t off = (size_t)b * NV;
    for (int i = blockIdx.x * 256 + threadIdx.x; i < nr; i += SSB * 256) {
        int c = rlR[i];
        ull k = minkey[off + c];         // final: scan is complete
        minkey[off + c] = ~0ULL;
        int e = (int)(k & 0xffffffffu);
        mask[(size_t)b * NE + e] = 1;
        int u, v; index_uv(e, u, v);
        int cu = comp[off + u], cv = comp[off + v];
        parent[off + c] = (cu == c) ? cv : cu;
    }
}

// Rounds 10..16 fused: one 512-thread block per batch (round-5-verified tail
// geometry), __syncthreads-ordered scan+select per round. Safe at entry 10:
// live edges decay ~2.5x/round, n@10 ~ hundreds — single-block latency costs
// ~1-3 us/round vs ~12 us/launch-pair replaced. Entry: scan(9) emitted into
// cnt[0]/list0 (TAIL_START even); converged batch sees cnt[0]==0 -> exit.
__global__ __launch_bounds__(TBLK) void tail_kernel(const ull* __restrict__ keys,
                                                    int* __restrict__ comp,
                                                    int* __restrict__ parent,
                                                    ull* __restrict__ minkey,
                                                    unsigned char* __restrict__ mask,
                                                    int* __restrict__ list0,
                                                    int* __restrict__ list1,
                                                    const int* __restrict__ cnt,
                                                    int* __restrict__ rootbuf) {
    const int b = blockIdx.x;
    const int tid = threadIdx.x;
    const int lane = tid & 63;
    const int wid = tid >> 6;
    const size_t offV = (size_t)b * NV;
    int* cmp = comp + offV;
    int* par = parent + offV;
    ull* mk = minkey + offV;
    const ull* ky = keys + (size_t)b * NE;
    unsigned char* msk = mask + (size_t)b * NE;
    int* la = list0 + (size_t)b * NE;
    int* lb = list1 + (size_t)b * NE;
    int* rb = rootbuf + (size_t)b * RB_CAP;

    __shared__ int s_out;             // survivors emitted this round
    __shared__ int s_nr;              // roots emitted this round
    __shared__ int s_wb[TBLK/64];     // per-wave emission bases

    int rpar = TAIL_START & 1;        // = 0: scan(9) emitted into list0/cnt[0]
    int n = cnt[rpar * NB * CSTR + b * CSTR];

    for (int r = TAIL_START; r < NROUNDS && n > 0; ++r) {
        const int* lr = rpar ? lb : la;
        int* lw = rpar ? la : lb;
        if (tid == 0) { s_out = 0; s_nr = 0; }
        __syncthreads();
        // ---- scan phase (uniform trip count; only wave-local LDS inside) ----
        for (int base = 0; base < n; base += TBLK * EPT) {
            int e[EPT], uu[EPT], vv[EPT], cu0[EPT], cv0[EPT], pu0[EPT], pv0[EPT];
            ull k[EPT];
            bool valid[EPT], live[EPT];
            #pragma unroll
            for (int j = 0; j < EPT; ++j) {
                int i = base + tid + j * TBLK;
                valid[j] = i < n;
                e[j] = valid[j] ? lr[i] : 0;
            }
            #pragma unroll
            for (int j = 0; j < EPT; ++j) {
                int u = 0, v = 0;
                if (valid[j]) index_uv(e[j], u, v);
                uu[j] = u; vv[j] = v;
            }
            #pragma unroll
            for (int j = 0; j < EPT; ++j) {
                cu0[j] = valid[j] ? cmp[uu[j]] : 0;
                cv0[j] = valid[j] ? cmp[vv[j]] : 0;
                k[j]   = valid[j] ? ky[e[j]] : 0;
            }
            #pragma unroll
            for (int j = 0; j < EPT; ++j) {
                pu0[j] = valid[j] ? par[cu0[j]] : 0;
                pv0[j] = valid[j] ? par[cv0[j]] : 0;
            }
            #pragma unroll
            for (int j = 0; j < EPT; ++j) {
                live[j] = false;
                if (valid[j]) {
                    int cu = rootOf2(par, cu0[j], pu0[j]);
                    int cv = rootOf2(par, cv0[j], pv0[j]);
                    if (cu0[j] != cu) cmp[uu[j]] = cu;   // benign race
                    if (cv0[j] != cv) cmp[vv[j]] = cv;
                    live[j] = (cu != cv);
                    if (live[j]) {
                        if (k[j] < mk[cu]) {
                            ull old = atomicMin(&mk[cu], k[j]);
                            if (old == ~0ULL) {
                                int ix = atomicAdd(&s_nr, 1);
                                if (ix < RB_CAP) rb[ix] = cu;   // first touch
                            }
                        }
                        if (k[j] < mk[cv]) {
                            ull old = atomicMin(&mk[cv], k[j]);
                            if (old == ~0ULL) {
                                int ix = atomicAdd(&s_nr, 1);
                                if (ix < RB_CAP) rb[ix] = cv;
                            }
                        }
                    }
                }
            }
            ull wl[EPT]; int wcnt = 0;
            #pragma unroll
            for (int j = 0; j < EPT; ++j) { wl[j] = __ballot(live[j] ? 1 : 0); wcnt += __popcll(wl[j]); }
            if (lane == 0) s_wb[wid] = wcnt ? atomicAdd(&s_out, wcnt) : 0;
            int pre = 0;
            #pragma unroll
            for (int j = 0; j < EPT; ++j) {      // s_wb[wid]: same-wave write->read, in-order LDS
                if (live[j]) {
                    int pos = s_wb[wid] + pre + __popcll(wl[j] & ((1ull << lane) - 1));
                    lw[pos] = e[j];
                }
                pre += __popcll(wl[j]);
            }
        }
        __syncthreads();                         // all atomicMins + emissions visible
        int nout = s_out;
        int nr = s_nr < RB_CAP ? s_nr : RB_CAP;
        // ---- sparse select over this round's roots ----
        for (int i = tid; i < nr; i += TBLK) {
            int c = rb[i];
            ull k = mk[c];                       // final: no concurrent atomics now
            mk[c] = ~0ULL;                       // reset touched slot
            int e = (int)(k & 0xffffffffu);
            msk[e] = 1;
            int u, v; index_uv(e, u, v);
            int cu = cmp[u], cv = cmp[v];
            par[c] = (cu == c) ? cv : cu;        // hook to "other" component
        }
        __syncthreads();                         // hooks visible before next scan
        n = nout;
        rpar ^= 1;
    }
}

__global__ __launch_bounds__(256) void count_kernel(const unsigned char* __restrict__ mask,
                                                    int* __restrict__ counts) {
    int b = blockIdx.y, ck = blockIdx.x, t = threadIdx.x;
    const unsigned char* m = mask + (size_t)b * NE;
    int base_e = ck * CHUNK + t * 16;
    int cnt = 0;
    #pragma unroll
    for (int i = 0; i < 16; ++i) {
        int e = base_e + i;
        if (e < NE && m[e]) cnt++;
    }
    __shared__ int sh[256];
    sh[t] = cnt;
    __syncthreads();
    for (int o = 128; o > 0; o >>= 1) {
        if (t < o) sh[t] += sh[t + o];
        __syncthreads();
    }
    if (t == 0) counts[b * NCHUNK + ck] = sh[0];
}

// Write with inline offset computation (reduce over counts[0..ck-1]).
__global__ __launch_bounds__(256) void write_kernel(const unsigned char* __restrict__ mask,
                                                    const int* __restrict__ counts,
                                                    int* __restrict__ out) {
    int b = blockIdx.y, ck = blockIdx.x, t = threadIdx.x;
    __shared__ int sh[256];
    __shared__ int shOff[128];
    shOff[t & 127] = 0;
    __syncthreads();
    if (t < NCHUNK && t < ck) shOff[t] = counts[b * NCHUNK + t];
    __syncthreads();
    for (int o = 64; o > 0; o >>= 1) {
        if (t < o) shOff[t] += shOff[t + o];
        __syncthreads();
    }
    int blockOff = shOff[0];

    const unsigned char* m = mask + (size_t)b * NE;
    int base_e = ck * CHUNK + t * 16;
    int cnt = 0;
    #pragma unroll
    for (int i = 0; i < 16; ++i) {
        int e = base_e + i;
        if (e < NE && m[e]) cnt++;
    }
    sh[t] = cnt;
    __syncthreads();
    for (int o = 1; o < 256; o <<= 1) {          // Hillis-Steele inclusive scan
        int v = 0;
        if (t >= o) v = sh[t - o];
        __syncthreads();
        sh[t] += v;
        __syncthreads();
    }
    int pos = blockOff + (sh[t] - cnt);
    for (int i = 0; i < 16; ++i) {
        int e = base_e + i;
        if (e < NE && m[e]) {
            if (pos < NTREE) out[(size_t)b * NTREE + pos] = e;
            pos++;
        }
    }
}

extern "C" void kernel_launch(void* const* d_in, const int* in_sizes, int n_in,
                              void* d_out, int out_size, void* d_ws, size_t ws_size,
                              hipStream_t stream) {
    const float* fm = (const float*)d_in[0];
    int* out = (int*)d_out;   // reference output dtype is int32

    char* ws = (char*)d_ws;
    size_t off = 0;
    auto alloc = [&](size_t bytes) -> void* {
        void* p = ws + off;
        off += (bytes + 255) & ~(size_t)255;
        return p;
    };
    ull* keys    = (ull*)alloc((size_t)NB * NE * 8);
    ull* minkey  = (ull*)alloc((size_t)NB * NV * 8);
    int* comp    = (int*)alloc((size_t)NB * NV * 4);
    int* parent  = (int*)alloc((size_t)NB * NV * 4);
    unsigned char* mask = (unsigned char*)alloc((size_t)NB * NE);
    int* list0   = (int*)alloc((size_t)NB * NE * 4);
    int* list1   = (int*)alloc((size_t)NB * NE * 4);
    int* cnt     = (int*)alloc(2 * NB * CSTR * 4);
    int* rl      = (int*)alloc(2 * (size_t)NB * RLCAP * 4);
    int* rlc     = (int*)alloc(2 * NB * CSTR * 4);
    int* rootbuf = (int*)alloc((size_t)NB * RB_CAP * 4);
    int* counts  = (int*)alloc((size_t)NB * NCHUNK * 4);

    dim3 blk(256);
    dim3 gE(NEB, NB);
    dim3 gE4(NEB4, NB);
    dim3 gV((NV + 255) / 256, NB);
    dim3 gVS((NV/4 + 255) / 256, NB);     // select0: 4 vertices/thread
    dim3 gL(SLB, NB);
    dim3 gS(SSB, NB);

    init_kernel<<<gE, blk, 0, stream>>>(comp, parent, minkey, mask, cnt, rlc);
    key0_kernel<<<gV, blk, 0, stream>>>(fm, keys, minkey);
    // Round 0: full select (every vertex is a winner; comp = identity).
    select0_kernel<<<gVS, blk, 0, stream>>>(comp, parent, minkey, mask);
    // Round 1: full edge sweep -> list0/cnt[0] + roots -> rl[1]/rlc[1].
    scan_full_kernel<<<gE4, blk, 0, stream>>>(keys, comp, parent, minkey,
                                              list0, cnt,
                                              rl + (size_t)NB * RLCAP,
                                              rlc + NB * CSTR);
    select_sparse_kernel<<<gS, blk, 0, stream>>>(comp, parent, minkey, mask,
                                                 rl + (size_t)NB * RLCAP,
                                                 rlc + NB * CSTR,
                                                 cnt + NB * CSTR,   // zero cnt[1]
                                                 rlc);              // zero rlc[0]
    // Rounds 2..9: scan(r) reads cnt[r&1] edges, emits cnt[(r+1)&1] + roots
    // rlc[r&1]; select(r) consumes rlc[r&1], zeroes cnt[r&1] & rlc[(r+1)&1].
    for (int r = 2; r < TAIL_START; ++r) {
        int rp = r & 1, ro = (r + 1) & 1;
        scan_list_kernel<<<gL, blk, 0, stream>>>(keys, comp, parent, minkey,
                                                 list0, list1, cnt, rp,
                                                 rl + (size_t)rp * NB * RLCAP,
                                                 rlc + rp * NB * CSTR);
        select_sparse_kernel<<<gS, blk, 0, stream>>>(comp, parent, minkey, mask,
                                                     rl + (size_t)rp * NB * RLCAP,
                                                     rlc + rp * NB * CSTR,
                                                     cnt + rp * NB * CSTR,
                                                     rlc + ro * NB * CSTR);
    }
    // Rounds 10..16: single-block-per-batch tail (launch-overhead elimination).
    tail_kernel<<<dim3(NB), dim3(TBLK), 0, stream>>>(keys, comp, parent, minkey,
                                                     mask, list0, list1, cnt,
                                                     rootbuf);

    count_kernel<<<dim3(NCHUNK, NB), blk, 0, stream>>>(mask, counts);
    write_kernel<<<dim3(NCHUNK, NB), blk, 0, stream>>>(mask, counts, out);
}